// Round 1
// baseline (714.873 us; speedup 1.0000x reference)
//
#include <hip/hip_runtime.h>
#include <math.h>

// Problem constants
#define N_ROWS 131072   // 32*64*64
#define D      64
#define K      512
#define BR     64       // rows per block
#define KC     128      // codes per LDS chunk
#define NCHUNK 4

// Output layout (float32, concatenated in reference return order)
#define OFF_Q    0LL
#define OFF_LOSS 8388608LL
#define OFF_PERP 8388609LL
#define OFF_ENC  8388610LL        // NOTE: ≡2 mod 4 -> only 8B aligned
#define OFF_IDX  75497474LL
#define OFF_DIST 75628546LL       // NOTE: ≡2 mod 4 -> only 8B aligned

// ---------------- codebook column norms: cn[k] = sum_d w[d][k]^2 ----------------
__global__ __launch_bounds__(512) void cn_kernel(const float* __restrict__ w,
                                                 float* __restrict__ cn) {
    int k = threadIdx.x;
    float s = 0.f;
    #pragma unroll
    for (int d = 0; d < D; ++d) { float t = w[d * K + k]; s += t * t; }
    cn[k] = s;
}

// ---------------- main fused kernel: 64 rows/block, all 512 codes ----------------
__global__ __launch_bounds__(256) void vq_main(const float* __restrict__ x,
                                               const float* __restrict__ w,
                                               const float* __restrict__ cn,
                                               float* __restrict__ out,
                                               double* __restrict__ loss_sum,
                                               int* __restrict__ hist) {
    __shared__ float xs[BR * 68];       // x tile, stride 68 (pad: bank-spread + 16B align)
    __shared__ float wsh[D * KC];       // w chunk [d][128]
    __shared__ float rn_s[BR];          // row norms
    __shared__ float red_min[BR];
    __shared__ int   red_idx[BR];

    const int tid = threadIdx.x;
    const int tc  = tid & 15;           // code group 0..15
    const int tr4 = (tid >> 4) * 4;     // first of 4 rows this thread owns
    const long long row0 = (long long)blockIdx.x * BR;

    // ---- stage x tile (64 rows x 64 d, contiguous 16KB in global) ----
    const float4* xg4 = (const float4*)(x + row0 * D);
    #pragma unroll
    for (int jj = 0; jj < 4; ++jj) {
        int q = jj * 256 + tid;               // float4 index 0..1023
        float4 v = xg4[q];
        int r = q >> 4; int d = (q & 15) * 4;
        *(float4*)&xs[r * 68 + d] = v;
    }
    __syncthreads();

    // row norms (one wave, one-time cost)
    if (tid < BR) {
        float s = 0.f;
        #pragma unroll
        for (int d = 0; d < D; ++d) { float t = xs[tid * 68 + d]; s += t * t; }
        rn_s[tid] = s;
    }

    float m[4]  = {3.4e38f, 3.4e38f, 3.4e38f, 3.4e38f};
    int   mi[4] = {0, 0, 0, 0};

    for (int c = 0; c < NCHUNK; ++c) {
        __syncthreads();   // protect wsh from previous chunk's readers (also covers rn_s writes)
        // ---- stage w chunk [64 d][128 codes] = 32KB ----
        const float4* wg4 = (const float4*)w;
        #pragma unroll
        for (int j = 0; j < 8; ++j) {
            int q = j * 256 + tid;            // float4 idx 0..2047
            int d = q >> 5; int cc4 = (q & 31);
            float4 v = wg4[d * (K / 4) + c * (KC / 4) + cc4];
            *(float4*)&wsh[d * KC + cc4 * 4] = v;
        }
        __syncthreads();

        // ---- register-tiled accumulation: 4 rows x 8 codes per thread ----
        float acc[4][8];
        #pragma unroll
        for (int i = 0; i < 4; ++i)
            #pragma unroll
            for (int j = 0; j < 8; ++j) acc[i][j] = 0.f;

        for (int d = 0; d < D; ++d) {
            float xv[4];
            #pragma unroll
            for (int i = 0; i < 4; ++i) xv[i] = xs[(tr4 + i) * 68 + d];
            float wv[8];
            *(float4*)&wv[0] = *(const float4*)&wsh[d * KC + tc * 4];        // codes tc*4..+3
            *(float4*)&wv[4] = *(const float4*)&wsh[d * KC + 64 + tc * 4];   // codes 64+tc*4..+3
            #pragma unroll
            for (int i = 0; i < 4; ++i)
                #pragma unroll
                for (int j = 0; j < 8; ++j) acc[i][j] += xv[i] * wv[j];
        }

        // ---- epilogue: distances + running argmin ----
        float cnv[8];
        *(float4*)&cnv[0] = *(const float4*)(cn + c * KC + tc * 4);
        *(float4*)&cnv[4] = *(const float4*)(cn + c * KC + 64 + tc * 4);
        const int kbA = c * KC + tc * 4;
        #pragma unroll
        for (int i = 0; i < 4; ++i) {
            int r = tr4 + i;
            float rn = rn_s[r];
            float v[8];
            #pragma unroll
            for (int j = 0; j < 8; ++j) v[j] = (rn - 2.f * acc[i][j]) + cnv[j];
            long long rowbase = OFF_DIST + (row0 + r) * (long long)K;
            // dist region is only 8B-aligned -> float2 stores
            *(float2*)(out + rowbase + kbA)          = make_float2(v[0], v[1]);
            *(float2*)(out + rowbase + kbA + 2)      = make_float2(v[2], v[3]);
            *(float2*)(out + rowbase + kbA + 64)     = make_float2(v[4], v[5]);
            *(float2*)(out + rowbase + kbA + 64 + 2) = make_float2(v[6], v[7]);
            #pragma unroll
            for (int j = 0; j < 4; ++j)
                if (v[j] < m[i]) { m[i] = v[j]; mi[i] = kbA + j; }
            #pragma unroll
            for (int j = 4; j < 8; ++j)
                if (v[j] < m[i]) { m[i] = v[j]; mi[i] = kbA + 64 + (j - 4); }
        }
    }

    // ---- cross-lane argmin over the 16 code-groups (first-index tie-break) ----
    #pragma unroll
    for (int i = 0; i < 4; ++i) {
        float mv = m[i]; int ki = mi[i];
        #pragma unroll
        for (int off = 1; off < 16; off <<= 1) {
            float om = __shfl_xor(mv, off);
            int   ok = __shfl_xor(ki, off);
            if (om < mv || (om == mv && ok < ki)) { mv = om; ki = ok; }
        }
        if (tc == 0) {
            int r = tr4 + i;
            red_min[r] = mv; red_idx[r] = ki;
            atomicAdd(&hist[ki], 1);
        }
    }
    __syncthreads();

    // ---- idx output + per-block loss contribution (sum of min distances) ----
    if (tid < BR) {
        out[OFF_IDX + row0 + tid] = (float)red_idx[tid];
        float v = red_min[tid];
        #pragma unroll
        for (int off = 1; off < 64; off <<= 1) v += __shfl_xor(v, off);
        if (tid == 0) atomicAdd(loss_sum, (double)v);
    }

    // ---- quantized (= w column gather): 4 threads per row, 16 d each ----
    {
        int r  = tid >> 2;
        int d0 = (tid & 3) * 16;
        int ks = red_idx[r];
        long long qbase = OFF_Q + (row0 + r) * (long long)D + d0;
        #pragma unroll
        for (int g = 0; g < 4; ++g) {
            float4 v;
            v.x = w[(d0 + g * 4 + 0) * K + ks];
            v.y = w[(d0 + g * 4 + 1) * K + ks];
            v.z = w[(d0 + g * 4 + 2) * K + ks];
            v.w = w[(d0 + g * 4 + 3) * K + ks];
            *(float4*)(out + qbase + g * 4) = v;
        }
    }

    // ---- one-hot encodings (8B-aligned region -> float2 stores) ----
    #pragma unroll 4
    for (int jj = 0; jj < 64; ++jj) {
        int q  = jj * 256 + tid;        // float2 index within 64x512 tile
        int r  = q >> 8;                // 256 float2 per row
        int k0 = (q & 255) * 2;
        int ks = red_idx[r];
        float2 v;
        v.x = (k0     == ks) ? 1.f : 0.f;
        v.y = (k0 + 1 == ks) ? 1.f : 0.f;
        *(float2*)(out + OFF_ENC + (row0 + r) * (long long)K + k0) = v;
    }
}

// ---------------- finalize: loss + perplexity ----------------
__global__ __launch_bounds__(512) void fin_kernel(const double* __restrict__ loss_sum,
                                                  const int* __restrict__ hist,
                                                  float* __restrict__ out) {
    __shared__ double sh[512];
    int t = threadIdx.x;
    double p = (double)hist[t] / (double)N_ROWS;
    sh[t] = p * log(p + 1e-10);
    __syncthreads();
    for (int s = 256; s > 0; s >>= 1) {
        if (t < s) sh[t] += sh[t + s];
        __syncthreads();
    }
    if (t == 0) {
        out[OFF_LOSS] = (float)(1.25 * (*loss_sum) / (double)(N_ROWS * D));
        out[OFF_PERP] = (float)exp(-sh[0]);
    }
}

extern "C" void kernel_launch(void* const* d_in, const int* in_sizes, int n_in,
                              void* d_out, int out_size, void* d_ws, size_t ws_size,
                              hipStream_t stream) {
    const float* x = (const float*)d_in[0];
    const float* w = (const float*)d_in[1];
    float* out = (float*)d_out;

    // workspace: [0,8) double loss_sum; [16,2064) float cn[512]; [2064,4112) int hist[512]
    double* loss_sum = (double*)d_ws;
    float*  cn       = (float*)((char*)d_ws + 16);
    int*    hist     = (int*)((char*)d_ws + 16 + 2048);

    hipMemsetAsync(d_ws, 0, 16 + 2048 + 2048, stream);
    cn_kernel<<<1, 512, 0, stream>>>(w, cn);
    vq_main<<<N_ROWS / BR, 256, 0, stream>>>(x, w, cn, out, loss_sum, hist);
    fin_kernel<<<1, 512, 0, stream>>>(loss_sum, hist, out);
}